// Round 1
// baseline (3630.263 us; speedup 1.0000x reference)
//
#include <hip/hip_runtime.h>

#define N_NODES 100000
#define N_EDGES 1600000
#define D 128

// ---------------------------------------------------------------------------
// GEMM: h[n][c] = sum_k x[n][k] * W[k][c]
// Block tile: 64 nodes x 64 cols, 256 threads, 4x4 register tile per thread.
// LDS: xs[64][132] (pad 4 -> float4 staging writes stay 16B aligned; main-loop
// row reads land 2-way bank aliased which is free), Wt[128][64].
// ---------------------------------------------------------------------------
__global__ __launch_bounds__(256) void gemm_kernel(const float* __restrict__ x,
                                                   const float* __restrict__ W,
                                                   float* __restrict__ h) {
    __shared__ float xs[64][132];
    __shared__ float Wt[128][64];

    const int tid = threadIdx.x;
    const int nodeBase = blockIdx.y * 64;
    const int colBase  = blockIdx.x * 64;

    // Stage x tile: 64 rows x 128 k = 2048 float4 / 256 threads = 8 reps.
    #pragma unroll
    for (int rep = 0; rep < 8; ++rep) {
        int idx  = tid + rep * 256;      // 0..2047
        int node = idx >> 5;             // 32 float4 per row
        int kk   = idx & 31;
        int gn   = nodeBase + node;
        float4 v = make_float4(0.f, 0.f, 0.f, 0.f);
        if (gn < N_NODES) v = *(const float4*)(x + (size_t)gn * D + kk * 4);
        *(float4*)(&xs[node][kk * 4]) = v;
    }
    // Stage W tile: 128 k x 64 cols = 2048 float4 ... wait, 8192 floats = 2048 float4
    #pragma unroll
    for (int rep = 0; rep < 8; ++rep) {
        int idx = tid + rep * 256;       // 0..2047
        int k   = idx >> 4;              // 16 float4 per 64-col row
        int cc  = idx & 15;
        float4 v = *(const float4*)(W + (size_t)k * D + colBase + cc * 4);
        *(float4*)(&Wt[k][cc * 4]) = v;
    }
    __syncthreads();

    const int ty = tid >> 4;             // 0..15 -> node group
    const int tx = tid & 15;             // 0..15 -> col group
    const int n0 = ty * 4;
    const int c0 = tx * 4;

    float acc[4][4];
    #pragma unroll
    for (int i = 0; i < 4; ++i)
        #pragma unroll
        for (int j = 0; j < 4; ++j) acc[i][j] = 0.f;

    #pragma unroll 4
    for (int k = 0; k < D; ++k) {
        float a0 = xs[n0 + 0][k];
        float a1 = xs[n0 + 1][k];
        float a2 = xs[n0 + 2][k];
        float a3 = xs[n0 + 3][k];
        float4 b = *(const float4*)(&Wt[k][c0]);
        acc[0][0] += a0 * b.x; acc[0][1] += a0 * b.y; acc[0][2] += a0 * b.z; acc[0][3] += a0 * b.w;
        acc[1][0] += a1 * b.x; acc[1][1] += a1 * b.y; acc[1][2] += a1 * b.z; acc[1][3] += a1 * b.w;
        acc[2][0] += a2 * b.x; acc[2][1] += a2 * b.y; acc[2][2] += a2 * b.z; acc[2][3] += a2 * b.w;
        acc[3][0] += a3 * b.x; acc[3][1] += a3 * b.y; acc[3][2] += a3 * b.z; acc[3][3] += a3 * b.w;
    }

    #pragma unroll
    for (int i = 0; i < 4; ++i) {
        int gn = nodeBase + n0 + i;
        if (gn < N_NODES) {
            float4 v = make_float4(acc[i][0], acc[i][1], acc[i][2], acc[i][3]);
            *(float4*)(h + (size_t)gn * D + colBase + c0) = v;
        }
    }
}

// ---------------------------------------------------------------------------
// init: out[n][d] = bias[d]  (harness poisons d_out with 0xAA every launch)
// one thread per float4; 3.2M threads.
// ---------------------------------------------------------------------------
__global__ __launch_bounds__(256) void init_out_kernel(const float* __restrict__ bias,
                                                       float* __restrict__ out) {
    int t = blockIdx.x * 256 + threadIdx.x;          // float4 index
    if (t >= N_NODES * D / 4) return;
    int c = (t & 31) * 4;                            // column within row
    float4 b = *(const float4*)(bias + c);
    *(float4*)(out + (size_t)t * 4) = b;
}

// ---------------------------------------------------------------------------
// scatter: for each edge e: out[dst] += relu(h[src] + edge_attr[e])
// 32 lanes per edge, 4 floats per lane (float4 loads), hw fp32 atomics.
// ---------------------------------------------------------------------------
__global__ __launch_bounds__(256) void scatter_kernel(const float* __restrict__ h,
                                                      const int* __restrict__ ei,
                                                      const float* __restrict__ ea,
                                                      float* __restrict__ out) {
    int t = blockIdx.x * 256 + threadIdx.x;          // 51.2M total
    int e = t >> 5;
    int l = t & 31;
    if (e >= N_EDGES) return;

    int src = ei[e];
    int dst = ei[N_EDGES + e];

    float4 m  = *(const float4*)(ea + (size_t)e * D + l * 4);
    float4 hv = *(const float4*)(h + (size_t)src * D + l * 4);

    float v0 = fmaxf(m.x + hv.x, 0.f);
    float v1 = fmaxf(m.y + hv.y, 0.f);
    float v2 = fmaxf(m.z + hv.z, 0.f);
    float v3 = fmaxf(m.w + hv.w, 0.f);

    float* op = out + (size_t)dst * D + l * 4;
    unsafeAtomicAdd(op + 0, v0);
    unsafeAtomicAdd(op + 1, v1);
    unsafeAtomicAdd(op + 2, v2);
    unsafeAtomicAdd(op + 3, v3);
}

extern "C" void kernel_launch(void* const* d_in, const int* in_sizes, int n_in,
                              void* d_out, int out_size, void* d_ws, size_t ws_size,
                              hipStream_t stream) {
    const float* x    = (const float*)d_in[0];
    const int*   ei   = (const int*)d_in[1];
    const float* ea   = (const float*)d_in[2];
    const float* W    = (const float*)d_in[3];
    const float* bias = (const float*)d_in[4];
    float* out = (float*)d_out;
    float* h   = (float*)d_ws;   // 100000*128*4 = 51.2 MB scratch

    dim3 gGemm(2, (N_NODES + 63) / 64);              // 2 col-blocks x 1563 node-blocks
    gemm_kernel<<<gGemm, 256, 0, stream>>>(x, W, h);

    init_out_kernel<<<(N_NODES * D / 4 + 255) / 256, 256, 0, stream>>>(bias, out);

    int scatterBlocks = (N_EDGES * 32 + 255) / 256;  // 200000
    scatter_kernel<<<scatterBlocks, 256, 0, stream>>>(h, ei, ea, out);
}